// Round 6
// baseline (12493.013 us; speedup 1.0000x reference)
//
#include <hip/hip_runtime.h>
#include <hip/hip_bf16.h>

#define L_SEQ 1024
#define NUMC  10000

// ---------------- mask (gumbel argmax) + L1 of alphas (256 threads) ----------
__global__ __launch_bounds__(256) void mask_l1_kernel(
    const float* __restrict__ alphas, const float* __restrict__ gumbel,
    float* __restrict__ msk, float* __restrict__ out)
{
    int tid = threadIdx.x;
    float la = 0.0f;
    #pragma unroll
    for (int rr = 0; rr < 4; ++rr) {
        int i = tid + rr * 256;
        float a0 = alphas[2*i],  a1 = alphas[2*i+1];
        float s0 = a0 + gumbel[2*i], s1 = a1 + gumbel[2*i+1];
        msk[i] = (s0 >= s1) ? 1.0f : 0.0f;   // argmax==0 -> m=1 (ties -> idx 0)
        la += fabsf(a0) + fabsf(a1);
    }
    #pragma unroll
    for (int o = 1; o < 64; o <<= 1) la += __shfl_xor(la, o);
    __shared__ float red[4];
    int lane = tid & 63, wid = tid >> 6;
    if (lane == 0) red[wid] = la;
    __syncthreads();
    if (tid == 0)
        out[8192] = red[0] + red[1] + red[2] + red[3];   // float32 output
}

// ---------------- embedding gathers ----------------
__global__ __launch_bounds__(128) void embed_x_kernel(
    const int* __restrict__ q, const int* __restrict__ r,
    const float* __restrict__ inter_emb, const float* __restrict__ pos_emb,
    float* __restrict__ x)
{
    int row = blockIdx.x;              // b*1024 + pos
    int pos = row & (L_SEQ - 1);
    int t = threadIdx.x;
    int e = q[row] + NUMC * r[row];
    float4 a = ((const float4*)(inter_emb + (size_t)e * 512))[t];
    float4 p = ((const float4*)(pos_emb + (size_t)pos * 512))[t];
    float4 o; o.x=a.x+p.x; o.y=a.y+p.y; o.z=a.z+p.z; o.w=a.w+p.w;
    ((float4*)(x + (size_t)row * 512))[t] = o;
}

__global__ __launch_bounds__(128) void embed_q_kernel(
    const int* __restrict__ qry, const float* __restrict__ ex_emb,
    float* __restrict__ qsh)
{
    int row = blockIdx.x;
    int t = threadIdx.x;
    ((float4*)(qsh + (size_t)row * 512))[t] =
        ((const float4*)(ex_emb + (size_t)qry[row] * 512))[t];
}

// ---------------- naive NT GEMM: one block per output row, K=512 -------------
// C[row][n] = sum_k A[row][k]*W[n][k] + bias[n] (+R[row][n]) (+relu)
__global__ __launch_bounds__(256) void gemm_naive(
    const float* __restrict__ A, const float* __restrict__ W,
    const float* __restrict__ bias, const float* __restrict__ R,
    void* __restrict__ C_, int c_bf, int N, int ldc, int relu)
{
    __shared__ __align__(16) float As[512];
    int row = blockIdx.x, t = threadIdx.x;
    ((float2*)As)[t] = ((const float2*)(A + (size_t)row * 512))[t];
    __syncthreads();
    for (int n = t; n < N; n += 256) {
        const float4* wr = (const float4*)(W + (size_t)n * 512);
        float acc = 0.0f;
        #pragma unroll 4
        for (int k4 = 0; k4 < 128; ++k4) {
            float4 w = wr[k4];
            float4 a = *(const float4*)&As[k4 << 2];
            acc += a.x*w.x + a.y*w.y + a.z*w.z + a.w*w.w;
        }
        float o = acc + bias[n];
        if (R) o += R[(size_t)row * 512 + n];
        if (relu) o = fmaxf(o, 0.0f);
        if (c_bf) ((__hip_bfloat16*)C_)[(size_t)row * ldc + n] = __float2bfloat16(o);
        else      ((float*)C_)[(size_t)row * ldc + n] = o;
    }
}

// ---------------- naive attention with fused Q-projection --------------------
// block = (q-row i, head h, batch b). qsh f32; KV bf16 (B*L,1024) K|V; O f32.
__global__ __launch_bounds__(256) void attn_naive(
    const float* __restrict__ qsh, const float* __restrict__ Wq,
    const float* __restrict__ bq, const __hip_bfloat16* __restrict__ KV,
    const float* __restrict__ msk, float* __restrict__ O)
{
    int i = blockIdx.x, h = blockIdx.y, b = blockIdx.z;
    size_t base = (size_t)b * L_SEQ;
    __shared__ float qrow[64];
    __shared__ float sc[L_SEQ];
    __shared__ float redm[4], reds[4];
    int t = threadIdx.x;
    // fused Q projection: qrow[d] = qsh[row] . Wq[h*64+d] + bq[h*64+d]
    if (t < 64) {
        const float* xr = qsh + (base + i) * 512;
        const float* wr = Wq + (size_t)(h * 64 + t) * 512;
        float acc = 0.0f;
        #pragma unroll 8
        for (int k = 0; k < 512; ++k) acc += xr[k] * wr[k];
        qrow[t] = acc + bq[h * 64 + t];
    }
    __syncthreads();
    // pass 1: masked scores for j in [0, i]
    float lmax = -INFINITY;
    for (int j = t; j <= i; j += 256) {
        const __hip_bfloat16* kr = KV + (base + j) * 1024 + h * 64;
        float s = 0.0f;
        #pragma unroll 16
        for (int d = 0; d < 64; ++d) s += qrow[d] * __bfloat162float(kr[d]);
        s *= 0.125f;
        if (msk[i - j] == 0.0f) s = -INFINITY;
        sc[j] = s;
        lmax = fmaxf(lmax, s);
    }
    #pragma unroll
    for (int o = 1; o < 64; o <<= 1) lmax = fmaxf(lmax, __shfl_xor(lmax, o));
    if ((t & 63) == 0) redm[t >> 6] = lmax;
    __syncthreads();
    float m = fmaxf(fmaxf(redm[0], redm[1]), fmaxf(redm[2], redm[3]));
    // pass 2: exp + sum (diagonal always allowed: m[0]=1 -> m finite)
    float lsum = 0.0f;
    for (int j = t; j <= i; j += 256) {
        float e = expf(sc[j] - m);
        sc[j] = e;
        lsum += e;
    }
    #pragma unroll
    for (int o = 1; o < 64; o <<= 1) lsum += __shfl_xor(lsum, o);
    if ((t & 63) == 0) reds[t >> 6] = lsum;
    __syncthreads();   // also publishes pass-2 sc[] writes
    float inv = 1.0f / (reds[0] + reds[1] + reds[2] + reds[3]);
    // PV: 64 threads, one output dim each
    if (t < 64) {
        float acc = 0.0f;
        for (int j = 0; j <= i; ++j)
            acc += sc[j] * __bfloat162float(KV[(base + j) * 1024 + 512 + h * 64 + t]);
        O[(base + i) * 512 + h * 64 + t] = acc * inv;
    }
}

// ---------------- row LayerNorm, in place ----------------
__global__ __launch_bounds__(128) void ln_kernel(float* __restrict__ X,
    const float* __restrict__ s, const float* __restrict__ b)
{
    int row = blockIdx.x, t = threadIdx.x;
    float* xp = X + (size_t)row * 512;
    float4 v = *((float4*)xp + t);
    float ps = v.x + v.y + v.z + v.w;
    #pragma unroll
    for (int o = 1; o < 64; o <<= 1) ps += __shfl_xor(ps, o);
    __shared__ float sm[4];
    int lane = t & 63, wid = t >> 6;
    if (lane == 0) sm[wid] = ps;
    __syncthreads();
    float mean = (sm[0] + sm[1]) * (1.0f / 512.0f);
    float4 d; d.x=v.x-mean; d.y=v.y-mean; d.z=v.z-mean; d.w=v.w-mean;
    float sq = d.x*d.x + d.y*d.y + d.z*d.z + d.w*d.w;
    #pragma unroll
    for (int o = 1; o < 64; o <<= 1) sq += __shfl_xor(sq, o);
    if (lane == 0) sm[2 + wid] = sq;
    __syncthreads();
    float inv = rsqrtf((sm[2] + sm[3]) * (1.0f / 512.0f) + 1e-5f);
    float4 sc = *((const float4*)s + t);
    float4 sh = *((const float4*)b + t);
    float4 o;
    o.x = d.x*inv*sc.x + sh.x; o.y = d.y*inv*sc.y + sh.y;
    o.z = d.z*inv*sc.z + sh.z; o.w = d.w*inv*sc.w + sh.w;
    *((float4*)xp + t) = o;
}

// ---------------- sigmoid head: f32 output ----------------
__global__ __launch_bounds__(256) void desakt_50629074485961_kernel(
    const float* __restrict__ x, const float* __restrict__ pw,
    const float* __restrict__ pb, float* __restrict__ out)
{
    int row = blockIdx.x * 4 + (threadIdx.x >> 6);
    int lane = threadIdx.x & 63;
    const float4* xr = (const float4*)(x + (size_t)row * 512) + lane * 2;
    const float4* wr = (const float4*)pw + lane * 2;
    float4 a0 = xr[0], a1 = xr[1], w0 = wr[0], w1 = wr[1];
    float s = a0.x*w0.x + a0.y*w0.y + a0.z*w0.z + a0.w*w0.w
            + a1.x*w1.x + a1.y*w1.y + a1.z*w1.z + a1.w*w1.w;
    #pragma unroll
    for (int o = 1; o < 64; o <<= 1) s += __shfl_xor(s, o);
    if (lane == 0) {
        float z = s + pb[0];
        out[row] = 1.0f / (1.0f + expf(-z));   // float32 output
    }
}

extern "C" __attribute__((visibility("default")))
void kernel_launch(void* const* d_in, const int* in_sizes, int n_in,
                   void* d_out, int out_size, void* d_ws, size_t ws_size,
                   hipStream_t stream) {
    (void)in_sizes; (void)n_in; (void)out_size;
    const int*   q        = (const int*)d_in[0];
    const int*   r        = (const int*)d_in[1];
    const int*   qry      = (const int*)d_in[2];
    const float* alphas   = (const float*)d_in[3];
    const float* gumbel   = (const float*)d_in[4];
    const float* inter_emb= (const float*)d_in[5];
    const float* ex_emb   = (const float*)d_in[6];
    const float* pos_emb  = (const float*)d_in[7];
    const float* Wqkv     = (const float*)d_in[8];
    const float* bqkv     = (const float*)d_in[9];
    const float* Wo       = (const float*)d_in[10];
    const float* bo       = (const float*)d_in[11];
    const float* ln1_s    = (const float*)d_in[12];
    const float* ln1_b    = (const float*)d_in[13];
    const float* W1       = (const float*)d_in[14];
    const float* b1       = (const float*)d_in[15];
    const float* W2       = (const float*)d_in[16];
    const float* b2       = (const float*)d_in[17];
    const float* ln2_s    = (const float*)d_in[18];
    const float* ln2_b    = (const float*)d_in[19];
    const float* pred_w   = (const float*)d_in[20];
    const float* pred_b   = (const float*)d_in[21];
    float* out            = (float*)d_out;     // reference output dtype = float32

    const size_t NT = 8192;
    const size_t needA = (1024 + 3 * NT * 512) * 4 + NT * 1024 * 2;  // ~67 MB
    float *msk, *x, *qsh, *t;
    __hip_bfloat16* kv;
    if (ws_size >= needA) {
        msk = (float*)d_ws;
        x   = msk + 1024;
        qsh = x   + NT * 512;
        t   = qsh + NT * 512;
        kv  = (__hip_bfloat16*)(t + NT * 512);
    } else {
        // small-ws fallback: park buffers in inputs that are dead after the
        // embedding gathers (inputs restored from pristine before every launch).
        // inter_emb = 40.96 MB holds qsh+t (32 MB); ex_emb = 20.5 MB holds kv (16 MB).
        msk = (float*)d_ws;                    // needs ws >= ~16.01 MB
        x   = msk + 1024;
        qsh = (float*)inter_emb;               // dead after embed_x
        t   = qsh + NT * 512;
        kv  = (__hip_bfloat16*)ex_emb;         // dead after embed_q
    }

    // capture-safe: kernel launches only, all on `stream`
    mask_l1_kernel<<<1, 256, 0, stream>>>(alphas, gumbel, msk, out);
    embed_x_kernel<<<8192, 128, 0, stream>>>(q, r, inter_emb, pos_emb, x);
    embed_q_kernel<<<8192, 128, 0, stream>>>(qry, ex_emb, qsh);

    for (int l = 0; l < 2; ++l) {
        const float* Wl = Wqkv + (size_t)l * 1536 * 512;
        const float* bl = bqkv + (size_t)l * 1536;
        // K,V projections from x -> kv (bf16), N=1024 spans Wk|Wv rows
        gemm_naive<<<8192, 256, 0, stream>>>(x, Wl + 512 * 512, bl + 512,
                                             nullptr, kv, 1, 1024, 1024, 0);
        // attention (Q fused from qsh) -> t
        attn_naive<<<dim3(L_SEQ, 8, 8), 256, 0, stream>>>(qsh, Wl, bl, kv, msk, t);
        // out proj + residual(qsh) -> x  (x dead after KV projection)
        gemm_naive<<<8192, 256, 0, stream>>>(t, Wo + (size_t)l * 512 * 512,
                                             bo + l * 512, qsh, x, 0, 512, 512, 0);
        ln_kernel<<<8192, 128, 0, stream>>>(x, ln1_s + l * 512, ln1_b + l * 512);
        // FF1 + relu: x(h) -> t
        gemm_naive<<<8192, 256, 0, stream>>>(x, W1 + (size_t)l * 512 * 512,
                                             b1 + l * 512, nullptr, t, 0, 512, 512, 1);
        // FF2 + residual(h=x) -> x  (same-element R/C is safe)
        gemm_naive<<<8192, 256, 0, stream>>>(t, W2 + (size_t)l * 512 * 512,
                                             b2 + l * 512, x, x, 0, 512, 512, 0);
        ln_kernel<<<8192, 128, 0, stream>>>(x, ln2_s + l * 512, ln2_b + l * 512);
    }
    desakt_50629074485961_kernel<<<2048, 256, 0, stream>>>(x, pred_w, pred_b, out);
}

// Round 7
// 5079.641 us; speedup vs baseline: 2.4594x; 2.4594x over previous
//
#include <hip/hip_runtime.h>
#include <hip/hip_bf16.h>

#define L_SEQ 1024
#define NUMC  10000

typedef __attribute__((ext_vector_type(8))) short bf16x8;
typedef __attribute__((ext_vector_type(4))) float f32x4;

// pack two f32 into two bf16 (RNE) in one u32 (lo = first elem)
__device__ __forceinline__ unsigned int bf2(float a, float b) {
    unsigned int ua = __float_as_uint(a);
    ua = (ua + 0x7fffu + ((ua >> 16) & 1u)) >> 16;
    unsigned int ub = __float_as_uint(b);
    ub = (ub + 0x7fffu + ((ub >> 16) & 1u)) >> 16;
    return ua | (ub << 16);
}

// ---------------- mask (gumbel argmax) + L1 of alphas ----------------
__global__ __launch_bounds__(256) void mask_l1_kernel(
    const float* __restrict__ alphas, const float* __restrict__ gumbel,
    float* __restrict__ msk, float* __restrict__ out)
{
    int tid = threadIdx.x;
    float la = 0.0f;
    #pragma unroll
    for (int rr = 0; rr < 4; ++rr) {
        int i = tid + rr * 256;
        float a0 = alphas[2*i],  a1 = alphas[2*i+1];
        float s0 = a0 + gumbel[2*i], s1 = a1 + gumbel[2*i+1];
        msk[i] = (s0 >= s1) ? 1.0f : 0.0f;   // argmax==0 -> m=1 (ties -> idx 0)
        la += fabsf(a0) + fabsf(a1);
    }
    #pragma unroll
    for (int o = 1; o < 64; o <<= 1) la += __shfl_xor(la, o);
    __shared__ float red[4];
    int lane = tid & 63, wid = tid >> 6;
    if (lane == 0) red[wid] = la;
    __syncthreads();
    if (tid == 0)
        out[8192] = red[0] + red[1] + red[2] + red[3];
}

// ---------------- embedding gathers ----------------
__global__ __launch_bounds__(128) void embed_x_kernel(
    const int* __restrict__ q, const int* __restrict__ r,
    const float* __restrict__ inter_emb, const float* __restrict__ pos_emb,
    float* __restrict__ x)
{
    int row = blockIdx.x;
    int pos = row & (L_SEQ - 1);
    int t = threadIdx.x;
    int e = q[row] + NUMC * r[row];
    float4 a = ((const float4*)(inter_emb + (size_t)e * 512))[t];
    float4 p = ((const float4*)(pos_emb + (size_t)pos * 512))[t];
    float4 o; o.x=a.x+p.x; o.y=a.y+p.y; o.z=a.z+p.z; o.w=a.w+p.w;
    ((float4*)(x + (size_t)row * 512))[t] = o;
}

__global__ __launch_bounds__(128) void embed_q_kernel(
    const int* __restrict__ qry, const float* __restrict__ ex_emb,
    float* __restrict__ qsh)
{
    int row = blockIdx.x;
    int t = threadIdx.x;
    ((float4*)(qsh + (size_t)row * 512))[t] =
        ((const float4*)(ex_emb + (size_t)qry[row] * 512))[t];
}

// ---------------- MFMA bf16 NT GEMM: C[m][n] = A[m][:] . W[n][:] -------------
// 128x128 tile, BK=64, 256 threads (4 waves 2x2), K=512 fixed.
// A,W f32 K-major; staged to LDS as bf16 with XOR swizzle. f32 accumulate.
__global__ __launch_bounds__(256) void gemm_mfma(
    const float* __restrict__ A, const float* __restrict__ W,
    const float* __restrict__ bias, const float* __restrict__ R,
    void* __restrict__ C_, int c_bf, int ldc, int relu)
{
    __shared__ __align__(16) char lsA[128 * 128];   // 128 rows x 64 bf16
    __shared__ __align__(16) char lsB[128 * 128];
    int t = threadIdx.x;
    int lane = t & 63, wid = t >> 6;
    int wr = wid >> 1, wc = wid & 1;
    int l15 = lane & 15, l4 = lane >> 4;
    int m0 = blockIdx.y * 128, n0 = blockIdx.x * 128;

    f32x4 zero = {0.f, 0.f, 0.f, 0.f};
    f32x4 acc[4][4];
    #pragma unroll
    for (int i = 0; i < 4; ++i)
        #pragma unroll
        for (int j = 0; j < 4; ++j) acc[i][j] = zero;

    for (int kt = 0; kt < 512; kt += 64) {
        float4 ra[4][2], rb[4][2];
        #pragma unroll
        for (int i = 0; i < 4; ++i) {
            int pp = t + (i << 8);
            int row = pp >> 3, c8 = pp & 7;
            const float* pa = A + (size_t)(m0 + row) * 512 + kt + (c8 << 3);
            ra[i][0] = *(const float4*)pa;
            ra[i][1] = *(const float4*)(pa + 4);
            const float* pb = W + (size_t)(n0 + row) * 512 + kt + (c8 << 3);
            rb[i][0] = *(const float4*)pb;
            rb[i][1] = *(const float4*)(pb + 4);
        }
        __syncthreads();   // prior iteration's LDS reads complete
        #pragma unroll
        for (int i = 0; i < 4; ++i) {
            int pp = t + (i << 8);
            int row = pp >> 3, c8 = pp & 7;
            int byte = ((row << 7) + (c8 << 4)) ^ ((row & 7) << 4);
            uint4 pk;
            pk.x = bf2(ra[i][0].x, ra[i][0].y);
            pk.y = bf2(ra[i][0].z, ra[i][0].w);
            pk.z = bf2(ra[i][1].x, ra[i][1].y);
            pk.w = bf2(ra[i][1].z, ra[i][1].w);
            *(uint4*)(lsA + byte) = pk;
            pk.x = bf2(rb[i][0].x, rb[i][0].y);
            pk.y = bf2(rb[i][0].z, rb[i][0].w);
            pk.z = bf2(rb[i][1].x, rb[i][1].y);
            pk.w = bf2(rb[i][1].z, rb[i][1].w);
            *(uint4*)(lsB + byte) = pk;
        }
        __syncthreads();
        #pragma unroll
        for (int kk = 0; kk < 2; ++kk) {
            bf16x8 af[4], bfv[4];
            #pragma unroll
            for (int i = 0; i < 4; ++i) {
                int rowA = (wr << 6) + (i << 4) + l15;
                int ba = ((rowA << 7) + (kk << 6) + (l4 << 4)) ^ ((rowA & 7) << 4);
                af[i] = *(const bf16x8*)(lsA + ba);
                int rowB = (wc << 6) + (i << 4) + l15;
                int bb = ((rowB << 7) + (kk << 6) + (l4 << 4)) ^ ((rowB & 7) << 4);
                bfv[i] = *(const bf16x8*)(lsB + bb);
            }
            #pragma unroll
            for (int i = 0; i < 4; ++i)
                #pragma unroll
                for (int j = 0; j < 4; ++j)
                    acc[i][j] = __builtin_amdgcn_mfma_f32_16x16x32_bf16(
                        af[i], bfv[j], acc[i][j], 0, 0, 0);
        }
    }
    // epilogue: C/D layout col=lane&15, row=(lane>>4)*4+reg
    float bv[4];
    #pragma unroll
    for (int j = 0; j < 4; ++j) bv[j] = bias[n0 + (wc << 6) + (j << 4) + l15];
    #pragma unroll
    for (int i = 0; i < 4; ++i) {
        #pragma unroll
        for (int r = 0; r < 4; ++r) {
            int grow = m0 + (wr << 6) + (i << 4) + (l4 << 2) + r;
            #pragma unroll
            for (int j = 0; j < 4; ++j) {
                int gcol = n0 + (wc << 6) + (j << 4) + l15;
                float o = acc[i][j][r] + bv[j];
                if (R) o += R[(size_t)grow * 512 + gcol];
                if (relu) o = fmaxf(o, 0.0f);
                if (c_bf) ((__hip_bfloat16*)C_)[(size_t)grow * ldc + gcol] = __float2bfloat16(o);
                else      ((float*)C_)[(size_t)grow * ldc + gcol] = o;
            }
        }
    }
}

// ---------------- attention: fused Q-proj, vectorized K-dot, 4-way PV --------
// block = (q-row i, head h, batch b). qsh f32; KV bf16 (B*L,1024) K|V; O f32.
__global__ __launch_bounds__(256) void attn_kernel(
    const float* __restrict__ qsh, const float* __restrict__ Wq,
    const float* __restrict__ bq, const __hip_bfloat16* __restrict__ KV,
    const float* __restrict__ msk, float* __restrict__ O)
{
    int i = blockIdx.x, h = blockIdx.y, b = blockIdx.z;
    size_t base = (size_t)b * L_SEQ;
    __shared__ float qrow[64];
    __shared__ float qpart[4][64];
    __shared__ float sc[L_SEQ];
    __shared__ float redm[4], reds[4];
    __shared__ float pv[4][64];
    int t = threadIdx.x;
    int d = t & 63, g = t >> 6;
    // Q projection: 4 k-partials per output dim, all 256 threads busy
    {
        const float* xr = qsh + (base + i) * 512 + g * 128;
        const float* wr = Wq + (size_t)(h * 64 + d) * 512 + g * 128;
        float acc = 0.f;
        #pragma unroll 8
        for (int k = 0; k < 128; k += 4) {
            float4 xv = *(const float4*)(xr + k);
            float4 wv = *(const float4*)(wr + k);
            acc += xv.x*wv.x + xv.y*wv.y + xv.z*wv.z + xv.w*wv.w;
        }
        qpart[g][d] = acc;
    }
    __syncthreads();
    if (t < 64)
        qrow[t] = qpart[0][t] + qpart[1][t] + qpart[2][t] + qpart[3][t] + bq[h*64 + t];
    __syncthreads();
    float qv[64];
    #pragma unroll
    for (int d2 = 0; d2 < 64; ++d2) qv[d2] = qrow[d2];
    // pass 1: masked scores for j in [0, i]  (bf16 K, bits<<16 exact convert)
    float lmax = -INFINITY;
    for (int j = t; j <= i; j += 256) {
        const uint4* kr = (const uint4*)(KV + (base + j) * 1024 + h * 64);
        float s = 0.f;
        #pragma unroll
        for (int c = 0; c < 8; ++c) {
            uint4 u = kr[c];
            const float* qq = qv + c * 8;
            s += __uint_as_float(u.x << 16)        * qq[0];
            s += __uint_as_float(u.x & 0xffff0000u) * qq[1];
            s += __uint_as_float(u.y << 16)        * qq[2];
            s += __uint_as_float(u.y & 0xffff0000u) * qq[3];
            s += __uint_as_float(u.z << 16)        * qq[4];
            s += __uint_as_float(u.z & 0xffff0000u) * qq[5];
            s += __uint_as_float(u.w << 16)        * qq[6];
            s += __uint_as_float(u.w & 0xffff0000u) * qq[7];
        }
        s *= 0.125f;
        if (msk[i - j] == 0.0f) s = -INFINITY;
        sc[j] = s;
        lmax = fmaxf(lmax, s);
    }
    #pragma unroll
    for (int o = 1; o < 64; o <<= 1) lmax = fmaxf(lmax, __shfl_xor(lmax, o));
    if ((t & 63) == 0) redm[t >> 6] = lmax;
    __syncthreads();
    float m = fmaxf(fmaxf(redm[0], redm[1]), fmaxf(redm[2], redm[3]));
    // pass 2: exp + sum (diagonal always allowed: m[0]=1 -> m finite)
    float lsum = 0.f;
    for (int j = t; j <= i; j += 256) {
        float e = __expf(sc[j] - m);
        sc[j] = e;
        lsum += e;
    }
    #pragma unroll
    for (int o = 1; o < 64; o <<= 1) lsum += __shfl_xor(lsum, o);
    if ((t & 63) == 0) reds[t >> 6] = lsum;
    __syncthreads();   // publishes pass-2 sc[] too
    float inv = 1.0f / (reds[0] + reds[1] + reds[2] + reds[3]);
    // PV: 4 j-groups x 64 dims
    float acc = 0.f;
    const unsigned short* Vp = (const unsigned short*)KV;
    for (int j = g; j <= i; j += 4)
        acc += sc[j] * __uint_as_float(
            ((unsigned int)Vp[(base + j) * 1024 + 512 + h * 64 + d]) << 16);
    pv[g][d] = acc;
    __syncthreads();
    if (t < 64)
        O[(base + i) * 512 + h * 64 + t] =
            (pv[0][t] + pv[1][t] + pv[2][t] + pv[3][t]) * inv;
}

// ---------------- row LayerNorm, in place ----------------
__global__ __launch_bounds__(128) void ln_kernel(float* __restrict__ X,
    const float* __restrict__ s, const float* __restrict__ b)
{
    int row = blockIdx.x, t = threadIdx.x;
    float* xp = X + (size_t)row * 512;
    float4 v = *((float4*)xp + t);
    float ps = v.x + v.y + v.z + v.w;
    #pragma unroll
    for (int o = 1; o < 64; o <<= 1) ps += __shfl_xor(ps, o);
    __shared__ float sm[4];
    int lane = t & 63, wid = t >> 6;
    if (lane == 0) sm[wid] = ps;
    __syncthreads();
    float mean = (sm[0] + sm[1]) * (1.0f / 512.0f);
    float4 d; d.x=v.x-mean; d.y=v.y-mean; d.z=v.z-mean; d.w=v.w-mean;
    float sq = d.x*d.x + d.y*d.y + d.z*d.z + d.w*d.w;
    #pragma unroll
    for (int o = 1; o < 64; o <<= 1) sq += __shfl_xor(sq, o);
    if (lane == 0) sm[2 + wid] = sq;
    __syncthreads();
    float inv = rsqrtf((sm[2] + sm[3]) * (1.0f / 512.0f) + 1e-5f);
    float4 sc = *((const float4*)s + t);
    float4 sh = *((const float4*)b + t);
    float4 o;
    o.x = d.x*inv*sc.x + sh.x; o.y = d.y*inv*sc.y + sh.y;
    o.z = d.z*inv*sc.z + sh.z; o.w = d.w*inv*sc.w + sh.w;
    *((float4*)xp + t) = o;
}

// ---------------- sigmoid head: f32 output ----------------
__global__ __launch_bounds__(256) void desakt_50629074485961_kernel(
    const float* __restrict__ x, const float* __restrict__ pw,
    const float* __restrict__ pb, float* __restrict__ out)
{
    int row = blockIdx.x * 4 + (threadIdx.x >> 6);
    int lane = threadIdx.x & 63;
    const float4* xr = (const float4*)(x + (size_t)row * 512) + lane * 2;
    const float4* wr = (const float4*)pw + lane * 2;
    float4 a0 = xr[0], a1 = xr[1], w0 = wr[0], w1 = wr[1];
    float s = a0.x*w0.x + a0.y*w0.y + a0.z*w0.z + a0.w*w0.w
            + a1.x*w1.x + a1.y*w1.y + a1.z*w1.z + a1.w*w1.w;
    #pragma unroll
    for (int o = 1; o < 64; o <<= 1) s += __shfl_xor(s, o);
    if (lane == 0) {
        float z = s + pb[0];
        out[row] = 1.0f / (1.0f + __expf(-z));
    }
}

extern "C" __attribute__((visibility("default")))
void kernel_launch(void* const* d_in, const int* in_sizes, int n_in,
                   void* d_out, int out_size, void* d_ws, size_t ws_size,
                   hipStream_t stream) {
    (void)in_sizes; (void)n_in; (void)out_size;
    const int*   q        = (const int*)d_in[0];
    const int*   r        = (const int*)d_in[1];
    const int*   qry      = (const int*)d_in[2];
    const float* alphas   = (const float*)d_in[3];
    const float* gumbel   = (const float*)d_in[4];
    const float* inter_emb= (const float*)d_in[5];
    const float* ex_emb   = (const float*)d_in[6];
    const float* pos_emb  = (const float*)d_in[7];
    const float* Wqkv     = (const float*)d_in[8];
    const float* bqkv     = (const float*)d_in[9];
    const float* Wo       = (const float*)d_in[10];
    const float* bo       = (const float*)d_in[11];
    const float* ln1_s    = (const float*)d_in[12];
    const float* ln1_b    = (const float*)d_in[13];
    const float* W1       = (const float*)d_in[14];
    const float* b1       = (const float*)d_in[15];
    const float* W2       = (const float*)d_in[16];
    const float* b2       = (const float*)d_in[17];
    const float* ln2_s    = (const float*)d_in[18];
    const float* ln2_b    = (const float*)d_in[19];
    const float* pred_w   = (const float*)d_in[20];
    const float* pred_b   = (const float*)d_in[21];
    float* out            = (float*)d_out;

    const size_t NT = 8192;
    const size_t needA = (1024 + 3 * NT * 512) * 4 + NT * 1024 * 2;  // ~67 MB
    float *msk, *x, *qsh, *t;
    __hip_bfloat16* kv;
    if (ws_size >= needA) {
        msk = (float*)d_ws;
        x   = msk + 1024;
        qsh = x   + NT * 512;
        t   = qsh + NT * 512;
        kv  = (__hip_bfloat16*)(t + NT * 512);
    } else {
        // small-ws fallback: park buffers in inputs dead after the gathers
        msk = (float*)d_ws;
        x   = msk + 1024;
        qsh = (float*)inter_emb;               // dead after embed_x
        t   = qsh + NT * 512;
        kv  = (__hip_bfloat16*)ex_emb;         // dead after embed_q
    }

    mask_l1_kernel<<<1, 256, 0, stream>>>(alphas, gumbel, msk, out);
    embed_x_kernel<<<8192, 128, 0, stream>>>(q, r, inter_emb, pos_emb, x);
    embed_q_kernel<<<8192, 128, 0, stream>>>(qry, ex_emb, qsh);

    for (int l = 0; l < 2; ++l) {
        const float* Wl = Wqkv + (size_t)l * 1536 * 512;
        const float* bl = bqkv + (size_t)l * 1536;
        // K,V projections from x -> kv (bf16, ldc=1024)
        gemm_mfma<<<dim3(8, 64), 256, 0, stream>>>(x, Wl + 512 * 512, bl + 512,
                                                   nullptr, kv, 1, 1024, 0);
        // attention (Q fused from qsh) -> t
        attn_kernel<<<dim3(L_SEQ, 8, 8), 256, 0, stream>>>(qsh, Wl, bl, kv, msk, t);
        // out proj + residual(qsh) -> x
        gemm_mfma<<<dim3(4, 64), 256, 0, stream>>>(t, Wo + (size_t)l * 512 * 512,
                                                   bo + l * 512, qsh, x, 0, 512, 0);
        ln_kernel<<<8192, 128, 0, stream>>>(x, ln1_s + l * 512, ln1_b + l * 512);
        // FF1 + relu: x(h) -> t
        gemm_mfma<<<dim3(4, 64), 256, 0, stream>>>(x, W1 + (size_t)l * 512 * 512,
                                                   b1 + l * 512, nullptr, t, 0, 512, 1);
        // FF2 + residual(h=x) -> x (same-element R/C safe)
        gemm_mfma<<<dim3(4, 64), 256, 0, stream>>>(t, W2 + (size_t)l * 512 * 512,
                                                   b2 + l * 512, x, x, 0, 512, 0);
        ln_kernel<<<8192, 128, 0, stream>>>(x, ln2_s + l * 512, ln2_b + l * 512);
    }
    desakt_50629074485961_kernel<<<2048, 256, 0, stream>>>(x, pred_w, pred_b, out);
}

// Round 8
// 710.027 us; speedup vs baseline: 17.5951x; 7.1542x over previous
//
#include <hip/hip_runtime.h>
#include <hip/hip_bf16.h>

#define L_SEQ 1024
#define NUMC  10000

typedef __attribute__((ext_vector_type(8))) short bf16x8;
typedef __attribute__((ext_vector_type(4))) float f32x4;

// pack two f32 into two bf16 (RNE) in one u32 (lo = first elem)
__device__ __forceinline__ unsigned int bf2(float a, float b) {
    unsigned int ua = __float_as_uint(a);
    ua = (ua + 0x7fffu + ((ua >> 16) & 1u)) >> 16;
    unsigned int ub = __float_as_uint(b);
    ub = (ub + 0x7fffu + ((ub >> 16) & 1u)) >> 16;
    return ua | (ub << 16);
}
__device__ __forceinline__ unsigned short bf1(float a) {
    unsigned int ua = __float_as_uint(a);
    return (unsigned short)((ua + 0x7fffu + ((ua >> 16) & 1u)) >> 16);
}

// ---------------- mask (gumbel argmax) + L1 of alphas ----------------
__global__ __launch_bounds__(256) void mask_l1_kernel(
    const float* __restrict__ alphas, const float* __restrict__ gumbel,
    float* __restrict__ msk, float* __restrict__ out)
{
    int tid = threadIdx.x;
    float la = 0.0f;
    #pragma unroll
    for (int rr = 0; rr < 4; ++rr) {
        int i = tid + rr * 256;
        float a0 = alphas[2*i],  a1 = alphas[2*i+1];
        float s0 = a0 + gumbel[2*i], s1 = a1 + gumbel[2*i+1];
        msk[i] = (s0 >= s1) ? 1.0f : 0.0f;
        la += fabsf(a0) + fabsf(a1);
    }
    #pragma unroll
    for (int o = 1; o < 64; o <<= 1) la += __shfl_xor(la, o);
    __shared__ float red[4];
    int lane = tid & 63, wid = tid >> 6;
    if (lane == 0) red[wid] = la;
    __syncthreads();
    if (tid == 0)
        out[8192] = red[0] + red[1] + red[2] + red[3];
}

// ---------------- embedding gathers ----------------
__global__ __launch_bounds__(128) void embed_x_kernel(
    const int* __restrict__ q, const int* __restrict__ r,
    const float* __restrict__ inter_emb, const float* __restrict__ pos_emb,
    float* __restrict__ x)
{
    int row = blockIdx.x;
    int pos = row & (L_SEQ - 1);
    int t = threadIdx.x;
    int e = q[row] + NUMC * r[row];
    float4 a = ((const float4*)(inter_emb + (size_t)e * 512))[t];
    float4 p = ((const float4*)(pos_emb + (size_t)pos * 512))[t];
    float4 o; o.x=a.x+p.x; o.y=a.y+p.y; o.z=a.z+p.z; o.w=a.w+p.w;
    ((float4*)(x + (size_t)row * 512))[t] = o;
}

__global__ __launch_bounds__(128) void embed_q_kernel(
    const int* __restrict__ qry, const float* __restrict__ ex_emb,
    float* __restrict__ qsh)
{
    int row = blockIdx.x;
    int t = threadIdx.x;
    ((float4*)(qsh + (size_t)row * 512))[t] =
        ((const float4*)(ex_emb + (size_t)qry[row] * 512))[t];
}

// ---------------- MFMA bf16 NT GEMM (proven round 7) -------------------------
__global__ __launch_bounds__(256) void gemm_mfma(
    const float* __restrict__ A, const float* __restrict__ W,
    const float* __restrict__ bias, const float* __restrict__ R,
    void* __restrict__ C_, int c_bf, int ldc, int relu)
{
    __shared__ __align__(16) char lsA[128 * 128];
    __shared__ __align__(16) char lsB[128 * 128];
    int t = threadIdx.x;
    int lane = t & 63, wid = t >> 6;
    int wr = wid >> 1, wc = wid & 1;
    int l15 = lane & 15, l4 = lane >> 4;
    int m0 = blockIdx.y * 128, n0 = blockIdx.x * 128;

    f32x4 zero = {0.f, 0.f, 0.f, 0.f};
    f32x4 acc[4][4];
    #pragma unroll
    for (int i = 0; i < 4; ++i)
        #pragma unroll
        for (int j = 0; j < 4; ++j) acc[i][j] = zero;

    for (int kt = 0; kt < 512; kt += 64) {
        float4 ra[4][2], rb[4][2];
        #pragma unroll
        for (int i = 0; i < 4; ++i) {
            int pp = t + (i << 8);
            int row = pp >> 3, c8 = pp & 7;
            const float* pa = A + (size_t)(m0 + row) * 512 + kt + (c8 << 3);
            ra[i][0] = *(const float4*)pa;
            ra[i][1] = *(const float4*)(pa + 4);
            const float* pb = W + (size_t)(n0 + row) * 512 + kt + (c8 << 3);
            rb[i][0] = *(const float4*)pb;
            rb[i][1] = *(const float4*)(pb + 4);
        }
        __syncthreads();
        #pragma unroll
        for (int i = 0; i < 4; ++i) {
            int pp = t + (i << 8);
            int row = pp >> 3, c8 = pp & 7;
            int byte = ((row << 7) + (c8 << 4)) ^ ((row & 7) << 4);
            uint4 pk;
            pk.x = bf2(ra[i][0].x, ra[i][0].y);
            pk.y = bf2(ra[i][0].z, ra[i][0].w);
            pk.z = bf2(ra[i][1].x, ra[i][1].y);
            pk.w = bf2(ra[i][1].z, ra[i][1].w);
            *(uint4*)(lsA + byte) = pk;
            pk.x = bf2(rb[i][0].x, rb[i][0].y);
            pk.y = bf2(rb[i][0].z, rb[i][0].w);
            pk.z = bf2(rb[i][1].x, rb[i][1].y);
            pk.w = bf2(rb[i][1].z, rb[i][1].w);
            *(uint4*)(lsB + byte) = pk;
        }
        __syncthreads();
        #pragma unroll
        for (int kk = 0; kk < 2; ++kk) {
            bf16x8 af[4], bfv[4];
            #pragma unroll
            for (int i = 0; i < 4; ++i) {
                int rowA = (wr << 6) + (i << 4) + l15;
                int ba = ((rowA << 7) + (kk << 6) + (l4 << 4)) ^ ((rowA & 7) << 4);
                af[i] = *(const bf16x8*)(lsA + ba);
                int rowB = (wc << 6) + (i << 4) + l15;
                int bb = ((rowB << 7) + (kk << 6) + (l4 << 4)) ^ ((rowB & 7) << 4);
                bfv[i] = *(const bf16x8*)(lsB + bb);
            }
            #pragma unroll
            for (int i = 0; i < 4; ++i)
                #pragma unroll
                for (int j = 0; j < 4; ++j)
                    acc[i][j] = __builtin_amdgcn_mfma_f32_16x16x32_bf16(
                        af[i], bfv[j], acc[i][j], 0, 0, 0);
        }
    }
    float bv[4];
    #pragma unroll
    for (int j = 0; j < 4; ++j) bv[j] = bias[n0 + (wc << 6) + (j << 4) + l15];
    #pragma unroll
    for (int i = 0; i < 4; ++i) {
        #pragma unroll
        for (int r = 0; r < 4; ++r) {
            int grow = m0 + (wr << 6) + (i << 4) + (l4 << 2) + r;
            #pragma unroll
            for (int j = 0; j < 4; ++j) {
                int gcol = n0 + (wc << 6) + (j << 4) + l15;
                float o = acc[i][j][r] + bv[j];
                if (R) o += R[(size_t)grow * 512 + gcol];
                if (relu) o = fmaxf(o, 0.0f);
                if (c_bf) ((__hip_bfloat16*)C_)[(size_t)grow * ldc + gcol] = __float2bfloat16(o);
                else      ((float*)C_)[(size_t)grow * ldc + gcol] = o;
            }
        }
    }
}

// ---------------- MFMA flash attention with fused Q-projection ---------------
// block = (q-tile 64, head, batch); 4 waves x 16 q-rows.
// qsh f32 (B*L,512); Wq rows h*64.. (512 cols); KV bf16 (B*L,1024) K|V; O f32.
__global__ __launch_bounds__(256) void attn_mfma(
    const float* __restrict__ qsh, const float* __restrict__ Wq,
    const float* __restrict__ bq, const __hip_bfloat16* __restrict__ KV,
    const float* __restrict__ msk, float* __restrict__ O)
{
    __shared__ __align__(16) char lsK[64 * 128];   // staging: qsh chunk, then K-tiles
    __shared__ __align__(16) char lsV[64 * 128];   // staging: Wq chunk, then V^T-tiles
    __shared__ __align__(16) char lsQ[64 * 128];   // Q-proj result (bf16, row=i, col=d)
    __shared__ __align__(16) char lsP[64 * 128];   // P tile (bf16, row=i, col=j)
    __shared__ float mskS[L_SEQ];
    int qt = blockIdx.x, h = blockIdx.y, b = blockIdx.z;
    int i0 = qt * 64;
    size_t base = (size_t)b * L_SEQ;
    int t = threadIdx.x;
    int lane = t & 63, w = t >> 6, l15 = lane & 15, l4 = lane >> 4;

    #pragma unroll
    for (int k = 0; k < 4; ++k) mskS[t + k * 256] = msk[t + k * 256];

    // ---- Q projection: q[i][d] = qsh[i0+i] . Wq[h*64+d] + bq ----
    f32x4 zero = {0.f, 0.f, 0.f, 0.f};
    f32x4 qa[4];
    #pragma unroll
    for (int j = 0; j < 4; ++j) qa[j] = zero;
    for (int kt = 0; kt < 512; kt += 64) {
        float4 ra[2][2], rb[2][2];
        #pragma unroll
        for (int i = 0; i < 2; ++i) {
            int p = t * 2 + i;                 // 0..511
            int row = p >> 3, c8 = p & 7;
            const float* pa = qsh + (base + i0 + row) * 512 + kt + (c8 << 3);
            ra[i][0] = *(const float4*)pa;  ra[i][1] = *(const float4*)(pa + 4);
            const float* pw = Wq + (size_t)(h * 64 + row) * 512 + kt + (c8 << 3);
            rb[i][0] = *(const float4*)pw;  rb[i][1] = *(const float4*)(pw + 4);
        }
        __syncthreads();   // prior iteration's fragment reads complete
        #pragma unroll
        for (int i = 0; i < 2; ++i) {
            int p = t * 2 + i;
            int row = p >> 3, c8 = p & 7;
            int byte = ((row << 7) + (c8 << 4)) ^ ((row & 7) << 4);
            uint4 pk;
            pk.x = bf2(ra[i][0].x, ra[i][0].y); pk.y = bf2(ra[i][0].z, ra[i][0].w);
            pk.z = bf2(ra[i][1].x, ra[i][1].y); pk.w = bf2(ra[i][1].z, ra[i][1].w);
            *(uint4*)(lsK + byte) = pk;
            pk.x = bf2(rb[i][0].x, rb[i][0].y); pk.y = bf2(rb[i][0].z, rb[i][0].w);
            pk.z = bf2(rb[i][1].x, rb[i][1].y); pk.w = bf2(rb[i][1].z, rb[i][1].w);
            *(uint4*)(lsV + byte) = pk;
        }
        __syncthreads();
        #pragma unroll
        for (int kk = 0; kk < 2; ++kk) {
            int ra_ = (w << 4) + l15;
            bf16x8 af = *(const bf16x8*)(lsK + (((ra_ << 7) + (kk << 6) + (l4 << 4)) ^ ((ra_ & 7) << 4)));
            #pragma unroll
            for (int df = 0; df < 4; ++df) {
                int rb_ = (df << 4) + l15;
                bf16x8 bf = *(const bf16x8*)(lsV + (((rb_ << 7) + (kk << 6) + (l4 << 4)) ^ ((rb_ & 7) << 4)));
                qa[df] = __builtin_amdgcn_mfma_f32_16x16x32_bf16(af, bf, qa[df], 0, 0, 0);
            }
        }
    }
    // bias + write q to lsQ (bf16, swizzled); rows w*16.. are wave-local
    #pragma unroll
    for (int df = 0; df < 4; ++df) {
        float bias = bq[h * 64 + (df << 4) + l15];
        #pragma unroll
        for (int r = 0; r < 4; ++r) {
            int row = (w << 4) + (l4 << 2) + r;
            int byte = ((row << 7) + (((df << 4) + l15) << 1)) ^ ((row & 7) << 4);
            *(unsigned short*)(lsQ + byte) = bf1(qa[df][r] + bias);
        }
    }

    // ---- online-softmax j-tile loop ----
    float mcur[4], lcur[4];
    f32x4 oa[4];
    #pragma unroll
    for (int r = 0; r < 4; ++r) { mcur[r] = -INFINITY; lcur[r] = 0.f; }
    #pragma unroll
    for (int df = 0; df < 4; ++df) oa[df] = zero;

    for (int jt = 0; jt <= qt; ++jt) {
        int j0 = jt * 64;
        __syncthreads();   // prior-tile reads done; also publishes lsQ on first iter
        #pragma unroll
        for (int i = 0; i < 2; ++i) {
            int p = t * 2 + i;
            int row = p >> 3, c8 = p & 7;    // row = j-local, c8*8 = d
            uint4 kv4 = *(const uint4*)(KV + (base + j0 + row) * 1024 + h * 64 + (c8 << 3));
            *(uint4*)(lsK + (((row << 7) + (c8 << 4)) ^ ((row & 7) << 4))) = kv4;
            uint4 vv = *(const uint4*)(KV + (base + j0 + row) * 1024 + 512 + h * 64 + (c8 << 3));
            const unsigned short* vs = (const unsigned short*)&vv;
            #pragma unroll
            for (int e = 0; e < 8; ++e) {    // transpose: lsV[d][j]
                int d = (c8 << 3) + e;
                *(unsigned short*)(lsV + (((d << 7) + (row << 1)) ^ ((d & 7) << 4))) = vs[e];
            }
        }
        __syncthreads();
        // S = Q K^T  (wave w: rows w*16..+15, cols 0..63)
        f32x4 s[4];
        #pragma unroll
        for (int jf = 0; jf < 4; ++jf) s[jf] = zero;
        #pragma unroll
        for (int kk = 0; kk < 2; ++kk) {
            int ra_ = (w << 4) + l15;
            bf16x8 af = *(const bf16x8*)(lsQ + (((ra_ << 7) + (kk << 6) + (l4 << 4)) ^ ((ra_ & 7) << 4)));
            #pragma unroll
            for (int jf = 0; jf < 4; ++jf) {
                int rb_ = (jf << 4) + l15;
                bf16x8 bf = *(const bf16x8*)(lsK + (((rb_ << 7) + (kk << 6) + (l4 << 4)) ^ ((rb_ & 7) << 4)));
                s[jf] = __builtin_amdgcn_mfma_f32_16x16x32_bf16(af, bf, s[jf], 0, 0, 0);
            }
        }
        // mask + online softmax (row r of C-layout: i = w*16 + l4*4 + r)
        #pragma unroll
        for (int r = 0; r < 4; ++r) {
            int gi = i0 + (w << 4) + (l4 << 2) + r;
            float rm = -INFINITY;
            #pragma unroll
            for (int jf = 0; jf < 4; ++jf) {
                int gj = j0 + (jf << 4) + l15;
                float v = s[jf][r] * 0.125f;
                bool ok = (gj <= gi) && (mskS[gi - gj] != 0.0f);
                v = ok ? v : -INFINITY;
                s[jf][r] = v;
                rm = fmaxf(rm, v);
            }
            #pragma unroll
            for (int o = 1; o < 16; o <<= 1) rm = fmaxf(rm, __shfl_xor(rm, o));
            float mn = fmaxf(mcur[r], rm);
            float c, psum = 0.f;
            if (mn == -INFINITY) {
                c = 1.0f;
                #pragma unroll
                for (int jf = 0; jf < 4; ++jf) s[jf][r] = 0.f;
            } else {
                c = __expf(mcur[r] - mn);
                #pragma unroll
                for (int jf = 0; jf < 4; ++jf) {
                    float e = __expf(s[jf][r] - mn);
                    s[jf][r] = e; psum += e;
                }
            }
            #pragma unroll
            for (int o = 1; o < 16; o <<= 1) psum += __shfl_xor(psum, o);
            mcur[r] = mn;
            lcur[r] = lcur[r] * c + psum;
            #pragma unroll
            for (int df = 0; df < 4; ++df) oa[df][r] *= c;
            int row = (w << 4) + (l4 << 2) + r;
            #pragma unroll
            for (int jf = 0; jf < 4; ++jf) {
                int byte = ((row << 7) + (((jf << 4) + l15) << 1)) ^ ((row & 7) << 4);
                *(unsigned short*)(lsP + byte) = bf1(s[jf][r]);
            }
        }
        __syncthreads();   // P visible
        // O += P V   (A = lsP rows i, k=j; B = lsV rows d, k=j)
        #pragma unroll
        for (int kk = 0; kk < 2; ++kk) {
            int ra_ = (w << 4) + l15;
            bf16x8 pf = *(const bf16x8*)(lsP + (((ra_ << 7) + (kk << 6) + (l4 << 4)) ^ ((ra_ & 7) << 4)));
            #pragma unroll
            for (int df = 0; df < 4; ++df) {
                int rb_ = (df << 4) + l15;
                bf16x8 vf = *(const bf16x8*)(lsV + (((rb_ << 7) + (kk << 6) + (l4 << 4)) ^ ((rb_ & 7) << 4)));
                oa[df] = __builtin_amdgcn_mfma_f32_16x16x32_bf16(pf, vf, oa[df], 0, 0, 0);
            }
        }
    }
    // epilogue
    #pragma unroll
    for (int r = 0; r < 4; ++r) {
        int gi = i0 + (w << 4) + (l4 << 2) + r;
        float inv = 1.0f / lcur[r];
        #pragma unroll
        for (int df = 0; df < 4; ++df)
            O[(base + gi) * 512 + h * 64 + (df << 4) + l15] = oa[df][r] * inv;
    }
}

// ---------------- row LayerNorm, in place ----------------
__global__ __launch_bounds__(128) void ln_kernel(float* __restrict__ X,
    const float* __restrict__ s, const float* __restrict__ b)
{
    int row = blockIdx.x, t = threadIdx.x;
    float* xp = X + (size_t)row * 512;
    float4 v = *((float4*)xp + t);
    float ps = v.x + v.y + v.z + v.w;
    #pragma unroll
    for (int o = 1; o < 64; o <<= 1) ps += __shfl_xor(ps, o);
    __shared__ float sm[4];
    int lane = t & 63, wid = t >> 6;
    if (lane == 0) sm[wid] = ps;
    __syncthreads();
    float mean = (sm[0] + sm[1]) * (1.0f / 512.0f);
    float4 d; d.x=v.x-mean; d.y=v.y-mean; d.z=v.z-mean; d.w=v.w-mean;
    float sq = d.x*d.x + d.y*d.y + d.z*d.z + d.w*d.w;
    #pragma unroll
    for (int o = 1; o < 64; o <<= 1) sq += __shfl_xor(sq, o);
    if (lane == 0) sm[2 + wid] = sq;
    __syncthreads();
    float inv = rsqrtf((sm[2] + sm[3]) * (1.0f / 512.0f) + 1e-5f);
    float4 sc = *((const float4*)s + t);
    float4 sh = *((const float4*)b + t);
    float4 o;
    o.x = d.x*inv*sc.x + sh.x; o.y = d.y*inv*sc.y + sh.y;
    o.z = d.z*inv*sc.z + sh.z; o.w = d.w*inv*sc.w + sh.w;
    *((float4*)xp + t) = o;
}

// ---------------- sigmoid head: f32 output ----------------
__global__ __launch_bounds__(256) void desakt_50629074485961_kernel(
    const float* __restrict__ x, const float* __restrict__ pw,
    const float* __restrict__ pb, float* __restrict__ out)
{
    int row = blockIdx.x * 4 + (threadIdx.x >> 6);
    int lane = threadIdx.x & 63;
    const float4* xr = (const float4*)(x + (size_t)row * 512) + lane * 2;
    const float4* wr = (const float4*)pw + lane * 2;
    float4 a0 = xr[0], a1 = xr[1], w0 = wr[0], w1 = wr[1];
    float s = a0.x*w0.x + a0.y*w0.y + a0.z*w0.z + a0.w*w0.w
            + a1.x*w1.x + a1.y*w1.y + a1.z*w1.z + a1.w*w1.w;
    #pragma unroll
    for (int o = 1; o < 64; o <<= 1) s += __shfl_xor(s, o);
    if (lane == 0) {
        float z = s + pb[0];
        out[row] = 1.0f / (1.0f + __expf(-z));
    }
}

extern "C" __attribute__((visibility("default")))
void kernel_launch(void* const* d_in, const int* in_sizes, int n_in,
                   void* d_out, int out_size, void* d_ws, size_t ws_size,
                   hipStream_t stream) {
    (void)in_sizes; (void)n_in; (void)out_size;
    const int*   q        = (const int*)d_in[0];
    const int*   r        = (const int*)d_in[1];
    const int*   qry      = (const int*)d_in[2];
    const float* alphas   = (const float*)d_in[3];
    const float* gumbel   = (const float*)d_in[4];
    const float* inter_emb= (const float*)d_in[5];
    const float* ex_emb   = (const float*)d_in[6];
    const float* pos_emb  = (const float*)d_in[7];
    const float* Wqkv     = (const float*)d_in[8];
    const float* bqkv     = (const float*)d_in[9];
    const float* Wo       = (const float*)d_in[10];
    const float* bo       = (const float*)d_in[11];
    const float* ln1_s    = (const float*)d_in[12];
    const float* ln1_b    = (const float*)d_in[13];
    const float* W1       = (const float*)d_in[14];
    const float* b1       = (const float*)d_in[15];
    const float* W2       = (const float*)d_in[16];
    const float* b2       = (const float*)d_in[17];
    const float* ln2_s    = (const float*)d_in[18];
    const float* ln2_b    = (const float*)d_in[19];
    const float* pred_w   = (const float*)d_in[20];
    const float* pred_b   = (const float*)d_in[21];
    float* out            = (float*)d_out;

    const size_t NT = 8192;
    const size_t needA = (1024 + 3 * NT * 512) * 4 + NT * 1024 * 2;  // ~67 MB
    float *msk, *x, *qsh, *t;
    __hip_bfloat16* kv;
    if (ws_size >= needA) {
        msk = (float*)d_ws;
        x   = msk + 1024;
        qsh = x   + NT * 512;
        t   = qsh + NT * 512;
        kv  = (__hip_bfloat16*)(t + NT * 512);
    } else {
        msk = (float*)d_ws;
        x   = msk + 1024;
        qsh = (float*)inter_emb;               // dead after embed_x
        t   = qsh + NT * 512;
        kv  = (__hip_bfloat16*)ex_emb;         // dead after embed_q
    }

    mask_l1_kernel<<<1, 256, 0, stream>>>(alphas, gumbel, msk, out);
    embed_x_kernel<<<8192, 128, 0, stream>>>(q, r, inter_emb, pos_emb, x);
    embed_q_kernel<<<8192, 128, 0, stream>>>(qry, ex_emb, qsh);

    for (int l = 0; l < 2; ++l) {
        const float* Wl = Wqkv + (size_t)l * 1536 * 512;
        const float* bl = bqkv + (size_t)l * 1536;
        // K,V projections from x -> kv (bf16, ldc=1024)
        gemm_mfma<<<dim3(8, 64), 256, 0, stream>>>(x, Wl + 512 * 512, bl + 512,
                                                   nullptr, kv, 1, 1024, 0);
        // MFMA flash attention (Q fused from qsh) -> t
        attn_mfma<<<dim3(16, 8, 8), 256, 0, stream>>>(qsh, Wl, bl, kv, msk, t);
        // out proj + residual(qsh) -> x
        gemm_mfma<<<dim3(4, 64), 256, 0, stream>>>(t, Wo + (size_t)l * 512 * 512,
                                                   bo + l * 512, qsh, x, 0, 512, 0);
        ln_kernel<<<8192, 128, 0, stream>>>(x, ln1_s + l * 512, ln1_b + l * 512);
        // FF1 + relu: x(h) -> t
        gemm_mfma<<<dim3(4, 64), 256, 0, stream>>>(x, W1 + (size_t)l * 512 * 512,
                                                   b1 + l * 512, nullptr, t, 0, 512, 1);
        // FF2 + residual(h=x) -> x
        gemm_mfma<<<dim3(4, 64), 256, 0, stream>>>(t, W2 + (size_t)l * 512 * 512,
                                                   b2 + l * 512, x, x, 0, 512, 0);
        ln_kernel<<<8192, 128, 0, stream>>>(x, ln2_s + l * 512, ln2_b + l * 512);
    }
    desakt_50629074485961_kernel<<<2048, 256, 0, stream>>>(x, pred_w, pred_b, out);
}

// Round 10
// 632.022 us; speedup vs baseline: 19.7667x; 1.1234x over previous
//
#include <hip/hip_runtime.h>
#include <hip/hip_bf16.h>

#define L_SEQ 1024
#define NUMC  10000

typedef __attribute__((ext_vector_type(8))) short bf16x8;
typedef __attribute__((ext_vector_type(4))) float f32x4;

// pack two f32 into two bf16 (RNE) in one u32 (lo = first elem)
__device__ __forceinline__ unsigned int bf2(float a, float b) {
    unsigned int ua = __float_as_uint(a);
    ua = (ua + 0x7fffu + ((ua >> 16) & 1u)) >> 16;
    unsigned int ub = __float_as_uint(b);
    ub = (ub + 0x7fffu + ((ub >> 16) & 1u)) >> 16;
    return ua | (ub << 16);
}
__device__ __forceinline__ unsigned short bf1(float a) {
    unsigned int ua = __float_as_uint(a);
    return (unsigned short)((ua + 0x7fffu + ((ua >> 16) & 1u)) >> 16);
}

// ---------------- mask (gumbel argmax) + L1 of alphas ----------------
__global__ __launch_bounds__(256) void mask_l1_kernel(
    const float* __restrict__ alphas, const float* __restrict__ gumbel,
    float* __restrict__ msk, float* __restrict__ out)
{
    int tid = threadIdx.x;
    float la = 0.0f;
    #pragma unroll
    for (int rr = 0; rr < 4; ++rr) {
        int i = tid + rr * 256;
        float a0 = alphas[2*i],  a1 = alphas[2*i+1];
        float s0 = a0 + gumbel[2*i], s1 = a1 + gumbel[2*i+1];
        msk[i] = (s0 >= s1) ? 1.0f : 0.0f;
        la += fabsf(a0) + fabsf(a1);
    }
    #pragma unroll
    for (int o = 1; o < 64; o <<= 1) la += __shfl_xor(la, o);
    __shared__ float red[4];
    int lane = tid & 63, wid = tid >> 6;
    if (lane == 0) red[wid] = la;
    __syncthreads();
    if (tid == 0)
        out[8192] = red[0] + red[1] + red[2] + red[3];
}

// ---------------- embedding gathers ----------------
__global__ __launch_bounds__(128) void embed_x_kernel(
    const int* __restrict__ q, const int* __restrict__ r,
    const float* __restrict__ inter_emb, const float* __restrict__ pos_emb,
    float* __restrict__ x)
{
    int row = blockIdx.x;
    int pos = row & (L_SEQ - 1);
    int t = threadIdx.x;
    int e = q[row] + NUMC * r[row];
    float4 a = ((const float4*)(inter_emb + (size_t)e * 512))[t];
    float4 p = ((const float4*)(pos_emb + (size_t)pos * 512))[t];
    float4 o; o.x=a.x+p.x; o.y=a.y+p.y; o.z=a.z+p.z; o.w=a.w+p.w;
    ((float4*)(x + (size_t)row * 512))[t] = o;
}

__global__ __launch_bounds__(128) void embed_q_kernel(
    const int* __restrict__ qry, const float* __restrict__ ex_emb,
    float* __restrict__ qsh)
{
    int row = blockIdx.x;
    int t = threadIdx.x;
    ((float4*)(qsh + (size_t)row * 512))[t] =
        ((const float4*)(ex_emb + (size_t)qry[row] * 512))[t];
}

// ---------------- MFMA bf16 NT GEMM (proven) ---------------------------------
__global__ __launch_bounds__(256) void gemm_mfma(
    const float* __restrict__ A, const float* __restrict__ W,
    const float* __restrict__ bias, const float* __restrict__ R,
    void* __restrict__ C_, int c_bf, int ldc, int relu)
{
    __shared__ __align__(16) char lsA[128 * 128];
    __shared__ __align__(16) char lsB[128 * 128];
    int t = threadIdx.x;
    int lane = t & 63, wid = t >> 6;
    int wr = wid >> 1, wc = wid & 1;
    int l15 = lane & 15, l4 = lane >> 4;
    int m0 = blockIdx.y * 128, n0 = blockIdx.x * 128;

    f32x4 zero = {0.f, 0.f, 0.f, 0.f};
    f32x4 acc[4][4];
    #pragma unroll
    for (int i = 0; i < 4; ++i)
        #pragma unroll
        for (int j = 0; j < 4; ++j) acc[i][j] = zero;

    for (int kt = 0; kt < 512; kt += 64) {
        float4 ra[4][2], rb[4][2];
        #pragma unroll
        for (int i = 0; i < 4; ++i) {
            int pp = t + (i << 8);
            int row = pp >> 3, c8 = pp & 7;
            const float* pa = A + (size_t)(m0 + row) * 512 + kt + (c8 << 3);
            ra[i][0] = *(const float4*)pa;
            ra[i][1] = *(const float4*)(pa + 4);
            const float* pb = W + (size_t)(n0 + row) * 512 + kt + (c8 << 3);
            rb[i][0] = *(const float4*)pb;
            rb[i][1] = *(const float4*)(pb + 4);
        }
        __syncthreads();
        #pragma unroll
        for (int i = 0; i < 4; ++i) {
            int pp = t + (i << 8);
            int row = pp >> 3, c8 = pp & 7;
            int byte = ((row << 7) + (c8 << 4)) ^ ((row & 7) << 4);
            uint4 pk;
            pk.x = bf2(ra[i][0].x, ra[i][0].y);
            pk.y = bf2(ra[i][0].z, ra[i][0].w);
            pk.z = bf2(ra[i][1].x, ra[i][1].y);
            pk.w = bf2(ra[i][1].z, ra[i][1].w);
            *(uint4*)(lsA + byte) = pk;
            pk.x = bf2(rb[i][0].x, rb[i][0].y);
            pk.y = bf2(rb[i][0].z, rb[i][0].w);
            pk.z = bf2(rb[i][1].x, rb[i][1].y);
            pk.w = bf2(rb[i][1].z, rb[i][1].w);
            *(uint4*)(lsB + byte) = pk;
        }
        __syncthreads();
        #pragma unroll
        for (int kk = 0; kk < 2; ++kk) {
            bf16x8 af[4], bfv[4];
            #pragma unroll
            for (int i = 0; i < 4; ++i) {
                int rowA = (wr << 6) + (i << 4) + l15;
                int ba = ((rowA << 7) + (kk << 6) + (l4 << 4)) ^ ((rowA & 7) << 4);
                af[i] = *(const bf16x8*)(lsA + ba);
                int rowB = (wc << 6) + (i << 4) + l15;
                int bb = ((rowB << 7) + (kk << 6) + (l4 << 4)) ^ ((rowB & 7) << 4);
                bfv[i] = *(const bf16x8*)(lsB + bb);
            }
            #pragma unroll
            for (int i = 0; i < 4; ++i)
                #pragma unroll
                for (int j = 0; j < 4; ++j)
                    acc[i][j] = __builtin_amdgcn_mfma_f32_16x16x32_bf16(
                        af[i], bfv[j], acc[i][j], 0, 0, 0);
        }
    }
    float bv[4];
    #pragma unroll
    for (int j = 0; j < 4; ++j) bv[j] = bias[n0 + (wc << 6) + (j << 4) + l15];
    #pragma unroll
    for (int i = 0; i < 4; ++i) {
        #pragma unroll
        for (int r = 0; r < 4; ++r) {
            int grow = m0 + (wr << 6) + (i << 4) + (l4 << 2) + r;
            #pragma unroll
            for (int j = 0; j < 4; ++j) {
                int gcol = n0 + (wc << 6) + (j << 4) + l15;
                float o = acc[i][j][r] + bv[j];
                if (R) o += R[(size_t)grow * 512 + gcol];
                if (relu) o = fmaxf(o, 0.0f);
                if (c_bf) ((__hip_bfloat16*)C_)[(size_t)grow * ldc + gcol] = __float2bfloat16(o);
                else      ((float*)C_)[(size_t)grow * ldc + gcol] = o;
            }
        }
    }
}

// ---------------- attention helpers ----------------
__device__ __forceinline__ void online_sm(
    f32x4 s[4], int i0, int j0, int w, int l4, int l15,
    const float* mskS, float mcur[4], float lcur[4], f32x4 oa[4], char* lsP)
{
    #pragma unroll
    for (int r = 0; r < 4; ++r) {
        int gi = i0 + (w << 4) + (l4 << 2) + r;
        float rm = -INFINITY;
        #pragma unroll
        for (int jf = 0; jf < 4; ++jf) {
            int gj = j0 + (jf << 4) + l15;
            float v = s[jf][r] * 0.125f;
            bool ok = (gj <= gi) && (mskS[gi - gj] != 0.0f);
            v = ok ? v : -INFINITY;
            s[jf][r] = v;
            rm = fmaxf(rm, v);
        }
        #pragma unroll
        for (int o = 1; o < 16; o <<= 1) rm = fmaxf(rm, __shfl_xor(rm, o));
        float mn = fmaxf(mcur[r], rm);
        float c, psum = 0.f;
        if (mn == -INFINITY) {
            c = 1.0f;
            #pragma unroll
            for (int jf = 0; jf < 4; ++jf) s[jf][r] = 0.f;
        } else {
            c = __expf(mcur[r] - mn);
            #pragma unroll
            for (int jf = 0; jf < 4; ++jf) {
                float e = __expf(s[jf][r] - mn);
                s[jf][r] = e; psum += e;
            }
        }
        #pragma unroll
        for (int o = 1; o < 16; o <<= 1) psum += __shfl_xor(psum, o);
        mcur[r] = mn;
        lcur[r] = lcur[r] * c + psum;
        #pragma unroll
        for (int df = 0; df < 4; ++df) oa[df][r] *= c;
        int row = (w << 4) + (l4 << 2) + r;
        #pragma unroll
        for (int jf = 0; jf < 4; ++jf) {
            int byte = ((row << 7) + (((jf << 4) + l15) << 1)) ^ ((row & 7) << 4);
            *(unsigned short*)(lsP + byte) = bf1(s[jf][r]);
        }
    }
}

__device__ __forceinline__ void pv_acc(
    const char* lsP, const char* lsV, int w, int l4, int l15, f32x4 oa[4])
{
    #pragma unroll
    for (int kk = 0; kk < 2; ++kk) {
        int ra_ = (w << 4) + l15;
        bf16x8 pf = *(const bf16x8*)(lsP + (((ra_ << 7) + (kk << 6) + (l4 << 4)) ^ ((ra_ & 7) << 4)));
        #pragma unroll
        for (int df = 0; df < 4; ++df) {
            int rb_ = (df << 4) + l15;
            bf16x8 vf = *(const bf16x8*)(lsV + (((rb_ << 7) + (kk << 6) + (l4 << 4)) ^ ((rb_ & 7) << 4)));
            oa[df] = __builtin_amdgcn_mfma_f32_16x16x32_bf16(pf, vf, oa[df], 0, 0, 0);
        }
    }
}

// ---------------- MFMA flash attention, cost-paired q-tiles ------------------
// block = (qp, head, batch): processes q-tiles qtA=qp and qtB=15-qp, sharing
// K/V staging (j-loop to qtB; tile-A pass only when jt<=qtA). Uniform cost.
// Q bf16 (B*L,512); KV bf16 (B*L,1024) K|V; O f32.
__global__ __launch_bounds__(256) void attn_mfma(
    const __hip_bfloat16* __restrict__ Qg, const __hip_bfloat16* __restrict__ KV,
    const float* __restrict__ msk, float* __restrict__ O)
{
    __shared__ __align__(16) char lsQA[64 * 128];
    __shared__ __align__(16) char lsQB[64 * 128];
    __shared__ __align__(16) char lsK[64 * 128];
    __shared__ __align__(16) char lsV[64 * 128];
    __shared__ __align__(16) char lsPA[64 * 128];
    __shared__ __align__(16) char lsPB[64 * 128];
    __shared__ float mskS[L_SEQ];
    int qp = blockIdx.x, h = blockIdx.y, b = blockIdx.z;
    int qtA = qp, qtB = 15 - qp;
    int i0A = qtA * 64, i0B = qtB * 64;
    size_t base = (size_t)b * L_SEQ;
    int t = threadIdx.x;
    int lane = t & 63, w = t >> 6, l15 = lane & 15, l4 = lane >> 4;

    #pragma unroll
    for (int k = 0; k < 4; ++k) mskS[t + k * 256] = msk[t + k * 256];
    // stage Q tiles (bf16 direct copy, swizzled)
    #pragma unroll
    for (int i = 0; i < 2; ++i) {
        int idx = t * 2 + i;              // 0..511
        int row = idx >> 3, c16 = idx & 7;
        int byte = ((row << 7) + (c16 << 4)) ^ ((row & 7) << 4);
        *(uint4*)(lsQA + byte) =
            *(const uint4*)(Qg + (base + i0A + row) * 512 + h * 64 + (c16 << 3));
        *(uint4*)(lsQB + byte) =
            *(const uint4*)(Qg + (base + i0B + row) * 512 + h * 64 + (c16 << 3));
    }

    f32x4 zero = {0.f, 0.f, 0.f, 0.f};
    float mA[4], lA[4], mB[4], lB[4];
    f32x4 oaA[4], oaB[4];
    #pragma unroll
    for (int r = 0; r < 4; ++r) { mA[r] = mB[r] = -INFINITY; lA[r] = lB[r] = 0.f; }
    #pragma unroll
    for (int df = 0; df < 4; ++df) { oaA[df] = zero; oaB[df] = zero; }

    for (int jt = 0; jt <= qtB; ++jt) {
        int j0 = jt * 64;
        __syncthreads();   // Q/msk visible (iter 0); prior PV reads done (later)
        // stage K (row-major, swizzled) + V^T (lsV[d][j], swizzled)
        #pragma unroll
        for (int i = 0; i < 2; ++i) {
            int idx = t * 2 + i;
            int row = idx >> 3, c8 = idx & 7;
            uint4 kv4 = *(const uint4*)(KV + (base + j0 + row) * 1024 + h * 64 + (c8 << 3));
            *(uint4*)(lsK + (((row << 7) + (c8 << 4)) ^ ((row & 7) << 4))) = kv4;
            uint4 vv = *(const uint4*)(KV + (base + j0 + row) * 1024 + 512 + h * 64 + (c8 << 3));
            const unsigned short* vs = (const unsigned short*)&vv;
            #pragma unroll
            for (int e = 0; e < 8; ++e) {
                int d = (c8 << 3) + e;
                *(unsigned short*)(lsV + (((d << 7) + (row << 1)) ^ ((d & 7) << 4))) = vs[e];
            }
        }
        __syncthreads();
        // S_B = Q_B K^T
        {
            f32x4 s[4];
            #pragma unroll
            for (int jf = 0; jf < 4; ++jf) s[jf] = zero;
            #pragma unroll
            for (int kk = 0; kk < 2; ++kk) {
                int ra_ = (w << 4) + l15;
                bf16x8 af = *(const bf16x8*)(lsQB + (((ra_ << 7) + (kk << 6) + (l4 << 4)) ^ ((ra_ & 7) << 4)));
                #pragma unroll
                for (int jf = 0; jf < 4; ++jf) {
                    int rb_ = (jf << 4) + l15;
                    bf16x8 bf = *(const bf16x8*)(lsK + (((rb_ << 7) + (kk << 6) + (l4 << 4)) ^ ((rb_ & 7) << 4)));
                    s[jf] = __builtin_amdgcn_mfma_f32_16x16x32_bf16(af, bf, s[jf], 0, 0, 0);
                }
            }
            online_sm(s, i0B, j0, w, l4, l15, mskS, mB, lB, oaB, lsPB);
        }
        // S_A (only while jt <= qtA)
        if (jt <= qtA) {
            f32x4 s[4];
            #pragma unroll
            for (int jf = 0; jf < 4; ++jf) s[jf] = zero;
            #pragma unroll
            for (int kk = 0; kk < 2; ++kk) {
                int ra_ = (w << 4) + l15;
                bf16x8 af = *(const bf16x8*)(lsQA + (((ra_ << 7) + (kk << 6) + (l4 << 4)) ^ ((ra_ & 7) << 4)));
                #pragma unroll
                for (int jf = 0; jf < 4; ++jf) {
                    int rb_ = (jf << 4) + l15;
                    bf16x8 bf = *(const bf16x8*)(lsK + (((rb_ << 7) + (kk << 6) + (l4 << 4)) ^ ((rb_ & 7) << 4)));
                    s[jf] = __builtin_amdgcn_mfma_f32_16x16x32_bf16(af, bf, s[jf], 0, 0, 0);
                }
            }
            online_sm(s, i0A, j0, w, l4, l15, mskS, mA, lA, oaA, lsPA);
        }
        __syncthreads();   // P visible
        pv_acc(lsPB, lsV, w, l4, l15, oaB);
        if (jt <= qtA) pv_acc(lsPA, lsV, w, l4, l15, oaA);
    }
    // epilogue
    #pragma unroll
    for (int r = 0; r < 4; ++r) {
        int giA = i0A + (w << 4) + (l4 << 2) + r;
        int giB = i0B + (w << 4) + (l4 << 2) + r;
        float invA = 1.0f / lA[r], invB = 1.0f / lB[r];
        #pragma unroll
        for (int df = 0; df < 4; ++df) {
            O[(base + giA) * 512 + h * 64 + (df << 4) + l15] = oaA[df][r] * invA;
            O[(base + giB) * 512 + h * 64 + (df << 4) + l15] = oaB[df][r] * invB;
        }
    }
}

// ---------------- row LayerNorm, in place ----------------
__global__ __launch_bounds__(128) void ln_kernel(float* __restrict__ X,
    const float* __restrict__ s, const float* __restrict__ b)
{
    int row = blockIdx.x, t = threadIdx.x;
    float* xp = X + (size_t)row * 512;
    float4 v = *((float4*)xp + t);
    float ps = v.x + v.y + v.z + v.w;
    #pragma unroll
    for (int o = 1; o < 64; o <<= 1) ps += __shfl_xor(ps, o);
    __shared__ float sm[4];
    int lane = t & 63, wid = t >> 6;
    if (lane == 0) sm[wid] = ps;
    __syncthreads();
    float mean = (sm[0] + sm[1]) * (1.0f / 512.0f);
    float4 d; d.x=v.x-mean; d.y=v.y-mean; d.z=v.z-mean; d.w=v.w-mean;
    float sq = d.x*d.x + d.y*d.y + d.z*d.z + d.w*d.w;
    #pragma unroll
    for (int o = 1; o < 64; o <<= 1) sq += __shfl_xor(sq, o);
    if (lane == 0) sm[2 + wid] = sq;
    __syncthreads();
    float inv = rsqrtf((sm[2] + sm[3]) * (1.0f / 512.0f) + 1e-5f);
    float4 sc = *((const float4*)s + t);
    float4 sh = *((const float4*)b + t);
    float4 o;
    o.x = d.x*inv*sc.x + sh.x; o.y = d.y*inv*sc.y + sh.y;
    o.z = d.z*inv*sc.z + sh.z; o.w = d.w*inv*sc.w + sh.w;
    *((float4*)xp + t) = o;
}

// ---------------- sigmoid head: f32 output ----------------
__global__ __launch_bounds__(256) void desakt_50629074485961_kernel(
    const float* __restrict__ x, const float* __restrict__ pw,
    const float* __restrict__ pb, float* __restrict__ out)
{
    int row = blockIdx.x * 4 + (threadIdx.x >> 6);
    int lane = threadIdx.x & 63;
    const float4* xr = (const float4*)(x + (size_t)row * 512) + lane * 2;
    const float4* wr = (const float4*)pw + lane * 2;
    float4 a0 = xr[0], a1 = xr[1], w0 = wr[0], w1 = wr[1];
    float s = a0.x*w0.x + a0.y*w0.y + a0.z*w0.z + a0.w*w0.w
            + a1.x*w1.x + a1.y*w1.y + a1.z*w1.z + a1.w*w1.w;
    #pragma unroll
    for (int o = 1; o < 64; o <<= 1) s += __shfl_xor(s, o);
    if (lane == 0) {
        float z = s + pb[0];
        out[row] = 1.0f / (1.0f + __expf(-z));
    }
}

extern "C" __attribute__((visibility("default")))
void kernel_launch(void* const* d_in, const int* in_sizes, int n_in,
                   void* d_out, int out_size, void* d_ws, size_t ws_size,
                   hipStream_t stream) {
    (void)in_sizes; (void)n_in; (void)out_size;
    const int*   q        = (const int*)d_in[0];
    const int*   r        = (const int*)d_in[1];
    const int*   qry      = (const int*)d_in[2];
    const float* alphas   = (const float*)d_in[3];
    const float* gumbel   = (const float*)d_in[4];
    const float* inter_emb= (const float*)d_in[5];
    const float* ex_emb   = (const float*)d_in[6];
    const float* pos_emb  = (const float*)d_in[7];
    const float* Wqkv     = (const float*)d_in[8];
    const float* bqkv     = (const float*)d_in[9];
    const float* Wo       = (const float*)d_in[10];
    const float* bo       = (const float*)d_in[11];
    const float* ln1_s    = (const float*)d_in[12];
    const float* ln1_b    = (const float*)d_in[13];
    const float* W1       = (const float*)d_in[14];
    const float* b1       = (const float*)d_in[15];
    const float* W2       = (const float*)d_in[16];
    const float* b2       = (const float*)d_in[17];
    const float* ln2_s    = (const float*)d_in[18];
    const float* ln2_b    = (const float*)d_in[19];
    const float* pred_w   = (const float*)d_in[20];
    const float* pred_b   = (const float*)d_in[21];
    float* out            = (float*)d_out;

    const size_t NT = 8192;
    // tier A: msk + x,qsh,t (f32) + qb (bf16, ld512) + kvb (bf16, ld1024)
    const size_t needA = (1024 + 3 * NT * 512) * 4 + NT * 512 * 2 + NT * 1024 * 2;
    float *msk, *x, *qsh, *t;
    __hip_bfloat16 *qb, *kvb;
    if (ws_size >= needA) {
        msk = (float*)d_ws;
        x   = msk + 1024;
        qsh = x   + NT * 512;
        t   = qsh + NT * 512;
        qb  = (__hip_bfloat16*)(t + NT * 512);
        kvb = qb + NT * 512;
    } else {
        // small-ws fallback: park in inputs dead after the embedding gathers
        msk = (float*)d_ws;                        // ws >= ~16.01 MB
        x   = msk + 1024;
        qsh = (float*)inter_emb;                   // inter_emb: 40.96 MB
        t   = qsh + NT * 512;                      //   [16..32) MB
        qb  = (__hip_bfloat16*)(t + NT * 512);     //   [32..40) MB (8 MB)
        kvb = (__hip_bfloat16*)ex_emb;             // ex_emb: 20.48 MB (16 MB used)
    }

    mask_l1_kernel<<<1, 256, 0, stream>>>(alphas, gumbel, msk, out);
    embed_x_kernel<<<8192, 128, 0, stream>>>(q, r, inter_emb, pos_emb, x);
    embed_q_kernel<<<8192, 128, 0, stream>>>(qry, ex_emb, qsh);

    for (int l = 0; l < 2; ++l) {
        const float* Wl = Wqkv + (size_t)l * 1536 * 512;
        const float* bl = bqkv + (size_t)l * 1536;
        // Q projection from qsh -> qb (bf16)
        gemm_mfma<<<dim3(4, 64), 256, 0, stream>>>(qsh, Wl, bl, nullptr, qb, 1, 512, 0);
        // K,V projections from x -> kvb (bf16)
        gemm_mfma<<<dim3(8, 64), 256, 0, stream>>>(x, Wl + 512 * 512, bl + 512,
                                                   nullptr, kvb, 1, 1024, 0);
        // paired-tile MFMA flash attention -> t
        attn_mfma<<<dim3(8, 8, 8), 256, 0, stream>>>(qb, kvb, msk, t);
        // out proj + residual(qsh) -> x
        gemm_mfma<<<dim3(4, 64), 256, 0, stream>>>(t, Wo + (size_t)l * 512 * 512,
                                                   bo + l * 512, qsh, x, 0, 512, 0);
        ln_kernel<<<8192, 128, 0, stream>>>(x, ln1_s + l * 512, ln1_b + l * 512);
        // FF1 + relu: x(h) -> t
        gemm_mfma<<<dim3(4, 64), 256, 0, stream>>>(x, W1 + (size_t)l * 512 * 512,
                                                   b1 + l * 512, nullptr, t, 0, 512, 1);
        // FF2 + residual(h=x) -> x
        gemm_mfma<<<dim3(4, 64), 256, 0, stream>>>(t, W2 + (size_t)l * 512 * 512,
                                                   b2 + l * 512, x, x, 0, 512, 0);
        ln_kernel<<<8192, 128, 0, stream>>>(x, ln2_s + l * 512, ln2_b + l * 512);
    }
    desakt_50629074485961_kernel<<<2048, 256, 0, stream>>>(x, pred_w, pred_b, out);
}